// Round 1
// baseline (452.161 us; speedup 1.0000x reference)
//
#include <hip/hip_runtime.h>

// Problem constants (match reference setup_inputs()).
#define U_DIM 128
#define NUM_OUT_SEG 16
#define C_DIM 300
#define S_DIM 32
#define NUM_X0 10
#define P1 32
#define P2 64
#define P3 96
#define P_TOT (P1 + P2 + P3)

typedef float vfloat4 __attribute__((ext_vector_type(4)));

// ---------------------------------------------------------------------------
// Prep kernel: counting-sort the 192 paths by key = o*3 + (deg-1) into 48
// contiguous runs.  Emits:
//   soff[49] ints at ws+0   (run boundaries; segment o spans [soff[3o],soff[3o+3]])
//   meta[192] int2 at ws+256: {w | s0<<9 | s1<<14 | s2<<19,  c_bits}
// Unused s-fields are 0 and never read (separate loop per degree).
// ---------------------------------------------------------------------------
__global__ void prep_kernel(const int* __restrict__ idx1, const int* __restrict__ w1,
                            const int* __restrict__ o1, const float* __restrict__ c1,
                            const int* __restrict__ idx2, const int* __restrict__ w2,
                            const int* __restrict__ o2, const float* __restrict__ c2,
                            const int* __restrict__ idx3, const int* __restrict__ w3,
                            const int* __restrict__ o3, const float* __restrict__ c3,
                            int* __restrict__ soff, int2* __restrict__ meta) {
    __shared__ int cnt[48];
    __shared__ int off[49];
    __shared__ int cur[48];
    const int t = threadIdx.x;
    if (t < 48) cnt[t] = 0;
    __syncthreads();

    int key = -1, packed = 0;
    float c = 0.f;
    if (t < P_TOT) {
        int deg, o, w, a0 = 0, a1 = 0, a2 = 0;
        if (t < P1) {
            int p = t;
            deg = 1; w = w1[p]; o = o1[p]; c = c1[p];
            a0 = idx1[p];
        } else if (t < P1 + P2) {
            int p = t - P1;
            deg = 2; w = w2[p]; o = o2[p]; c = c2[p];
            a0 = idx2[2 * p]; a1 = idx2[2 * p + 1];
        } else {
            int p = t - P1 - P2;
            deg = 3; w = w3[p]; o = o3[p]; c = c3[p];
            a0 = idx3[3 * p]; a1 = idx3[3 * p + 1]; a2 = idx3[3 * p + 2];
        }
        key = o * 3 + (deg - 1);
        packed = w | (a0 << 9) | (a1 << 14) | (a2 << 19);
        atomicAdd(&cnt[key], 1);
    }
    __syncthreads();
    if (t == 0) {
        int a = 0;
        for (int k = 0; k < 48; ++k) { off[k] = a; a += cnt[k]; }
        off[48] = a;
    }
    __syncthreads();
    if (t < 49) soff[t] = off[t];
    if (t < 48) cur[t] = off[t];
    __syncthreads();
    if (t < P_TOT) {
        int r = atomicAdd(&cur[key], 1);
        meta[r] = make_int2(packed, __float_as_int(c));
    }
}

// Direct global->LDS async copy, 16B per lane. LDS destination must be
// wave-uniform base + lane*16 (it is: dst index is linear in tid).
__device__ __forceinline__ void gload_lds16(const void* g, void* l) {
    __builtin_amdgcn_global_load_lds(
        (const __attribute__((address_space(1))) unsigned int*)g,
        (__attribute__((address_space(3))) unsigned int*)l, 16, 0, 0);
}

// ---------------------------------------------------------------------------
// Main kernel: block = 512 threads = 8 waves = 2 batch rows.
// Each wave processes TWO output segments sequentially; the wave->segment
// map is rotated by blockIdx so heavy segments don't pin to the same SIMD
// in every block (persistent per-SIMD imbalance fix).  Lanes 0-31 = row 0,
// lanes 32-63 = row 1, one float4 chunk per lane (b128 LDS reads).
// LDS ~34 kB, launch_bounds(512,8) -> 4 blocks/CU = 32 waves/CU = 100% occ;
// 4 resident blocks stagger their staging barriers (vs 2 before), hiding
// the vmcnt(0) drain of the x1 stage under other blocks' compute.
// x1 staging uses global_load_lds (no VGPR round-trip, no ds_write issue).
// ---------------------------------------------------------------------------
__global__ __launch_bounds__(512, 8) void contract_kernel(
    const float* __restrict__ x0, const int* __restrict__ i0,
    const float* __restrict__ x1, const int* __restrict__ soff,
    const int2* __restrict__ gmeta, float* __restrict__ out) {
    __shared__ vfloat4 x1s[2 * S_DIM * 32];  // [row][s][chunk], 32 kB
    __shared__ int2 smeta[P_TOT];            // 1.5 kB
    __shared__ int soffs[49];

    const int tid = threadIdx.x;
    const int wave = tid >> 6;   // 0..7
    const int lane = tid & 63;
    const int h = lane >> 5;     // row within the pair
    const int ch = lane & 31;    // float4 chunk (covers U=128)
    const long b0 = (long)blockIdx.x * 2;

    // Stage 2 rows of x1 (2048 float4) directly into LDS: 4 x 16B per lane,
    // linear layout -> legal wave-uniform-base + lane*16 destinations.
    const vfloat4* x1p = (const vfloat4*)(x1 + b0 * (S_DIM * U_DIM));
#pragma unroll
    for (int i = 0; i < 4; ++i)
        gload_lds16(x1p + tid + i * 512, &x1s[tid + i * 512]);
    if (tid < P_TOT) smeta[tid] = gmeta[tid];
    if (tid < 49) soffs[tid] = soff[tid];

    const int elem = i0[b0 + h];
    const vfloat4* gseg = (const vfloat4*)x0 + (long)elem * (C_DIM * 32) + ch;
    const vfloat4* myx1 = x1s + h * (S_DIM * 32) + ch;
    float* outrow = out + (b0 + h) * (NUM_OUT_SEG * U_DIM);

    __syncthreads();  // drains vmcnt(0): global_load_lds data is in LDS

    const int rot = (int)blockIdx.x & 15;

#pragma unroll
    for (int half = 0; half < 2; ++half) {
        const int sg = (wave + half * 8 + rot) & 15;  // actual output segment
        int p = soffs[sg * 3];
        const int e1 = soffs[sg * 3 + 1];
        const int e2 = soffs[sg * 3 + 2];
        const int e3 = soffs[sg * 3 + 3];
        vfloat4 acc = (vfloat4)(0.f);

        // degree-1 run
#pragma unroll 2
        for (; p < e1; ++p) {
            int2 m = smeta[p];
            float cc = __int_as_float(m.y);
            vfloat4 g = gseg[(m.x & 0x1FF) * 32];
            vfloat4 xa = myx1[((m.x >> 9) & 31) * 32];
            acc += (cc * g) * xa;
        }
        // degree-2 run
#pragma unroll 2
        for (; p < e2; ++p) {
            int2 m = smeta[p];
            float cc = __int_as_float(m.y);
            vfloat4 g = gseg[(m.x & 0x1FF) * 32];
            vfloat4 xa = myx1[((m.x >> 9) & 31) * 32];
            vfloat4 xb = myx1[((m.x >> 14) & 31) * 32];
            acc += (cc * g) * (xa * xb);
        }
        // degree-3 run
#pragma unroll 2
        for (; p < e3; ++p) {
            int2 m = smeta[p];
            float cc = __int_as_float(m.y);
            vfloat4 g = gseg[(m.x & 0x1FF) * 32];
            vfloat4 xa = myx1[((m.x >> 9) & 31) * 32];
            vfloat4 xb = myx1[((m.x >> 14) & 31) * 32];
            vfloat4 xc = myx1[((m.x >> 19) & 31) * 32];
            acc += (cc * g) * (xa * xb * xc);
        }

        // Streamed output (no reuse): nontemporal, coalesced 512B per half-wave.
        vfloat4* outp = (vfloat4*)outrow + sg * 32 + ch;
        __builtin_nontemporal_store(acc, outp);
    }
}

extern "C" void kernel_launch(void* const* d_in, const int* in_sizes, int n_in,
                              void* d_out, int out_size, void* d_ws, size_t ws_size,
                              hipStream_t stream) {
    const float* x0 = (const float*)d_in[0];
    const int* i0 = (const int*)d_in[1];
    const float* x1 = (const float*)d_in[2];
    const int* idx1 = (const int*)d_in[3];
    const int* w1 = (const int*)d_in[4];
    const int* o1 = (const int*)d_in[5];
    const float* c1 = (const float*)d_in[6];
    const int* idx2 = (const int*)d_in[7];
    const int* w2 = (const int*)d_in[8];
    const int* o2 = (const int*)d_in[9];
    const float* c2 = (const float*)d_in[10];
    const int* idx3 = (const int*)d_in[11];
    const int* w3 = (const int*)d_in[12];
    const int* o3 = (const int*)d_in[13];
    const float* c3 = (const float*)d_in[14];

    int* soff = (int*)d_ws;
    int2* meta = (int2*)((char*)d_ws + 256);

    const int B = in_sizes[1];  // 16384

    prep_kernel<<<1, 256, 0, stream>>>(idx1, w1, o1, c1, idx2, w2, o2, c2,
                                       idx3, w3, o3, c3, soff, meta);
    contract_kernel<<<B / 2, 512, 0, stream>>>(x0, i0, x1, soff, meta, (float*)d_out);
}

// Round 2
// 447.983 us; speedup vs baseline: 1.0093x; 1.0093x over previous
//
#include <hip/hip_runtime.h>

// Problem constants (match reference setup_inputs()).
#define U_DIM 128
#define NUM_OUT_SEG 16
#define C_DIM 300
#define S_DIM 32
#define NUM_X0 10
#define P1 32
#define P2 64
#define P3 96
#define P_TOT (P1 + P2 + P3)

typedef float vfloat4 __attribute__((ext_vector_type(4)));

// ---------------------------------------------------------------------------
// Prep kernel: counting-sort the 192 paths by key = o*3 + (deg-1) into 48
// contiguous runs.  Emits:
//   soff[49] ints at ws+0   (run boundaries; segment o spans [soff[3o],soff[3o+3]])
//   meta[192] int2 at ws+256: {w | s0<<9 | s1<<14 | s2<<19,  c_bits}
// Unused s-fields are 0 and never read (separate loop per degree).
// ---------------------------------------------------------------------------
__global__ void prep_kernel(const int* __restrict__ idx1, const int* __restrict__ w1,
                            const int* __restrict__ o1, const float* __restrict__ c1,
                            const int* __restrict__ idx2, const int* __restrict__ w2,
                            const int* __restrict__ o2, const float* __restrict__ c2,
                            const int* __restrict__ idx3, const int* __restrict__ w3,
                            const int* __restrict__ o3, const float* __restrict__ c3,
                            int* __restrict__ soff, int2* __restrict__ meta) {
    __shared__ int cnt[48];
    __shared__ int off[49];
    __shared__ int cur[48];
    const int t = threadIdx.x;
    if (t < 48) cnt[t] = 0;
    __syncthreads();

    int key = -1, packed = 0;
    float c = 0.f;
    if (t < P_TOT) {
        int deg, o, w, a0 = 0, a1 = 0, a2 = 0;
        if (t < P1) {
            int p = t;
            deg = 1; w = w1[p]; o = o1[p]; c = c1[p];
            a0 = idx1[p];
        } else if (t < P1 + P2) {
            int p = t - P1;
            deg = 2; w = w2[p]; o = o2[p]; c = c2[p];
            a0 = idx2[2 * p]; a1 = idx2[2 * p + 1];
        } else {
            int p = t - P1 - P2;
            deg = 3; w = w3[p]; o = o3[p]; c = c3[p];
            a0 = idx3[3 * p]; a1 = idx3[3 * p + 1]; a2 = idx3[3 * p + 2];
        }
        key = o * 3 + (deg - 1);
        packed = w | (a0 << 9) | (a1 << 14) | (a2 << 19);
        atomicAdd(&cnt[key], 1);
    }
    __syncthreads();
    if (t == 0) {
        int a = 0;
        for (int k = 0; k < 48; ++k) { off[k] = a; a += cnt[k]; }
        off[48] = a;
    }
    __syncthreads();
    if (t < 49) soff[t] = off[t];
    if (t < 48) cur[t] = off[t];
    __syncthreads();
    if (t < P_TOT) {
        int r = atomicAdd(&cur[key], 1);
        meta[r] = make_int2(packed, __float_as_int(c));
    }
}

// ---------------------------------------------------------------------------
// Scale kernel: materialize g0c[e][r][u] = c[r] * x0[e][w[r]*U + u] in the
// SORTED path order r.  983 KB -> fits every XCD's L2.  In the contract
// kernel the x0-side address becomes linear in the loop index p (no
// dependency on the meta LDS read), and the per-path coefficient multiply
// disappears.  One vfloat4 per thread: 10*192*32 = 61440 threads.
// ---------------------------------------------------------------------------
__global__ __launch_bounds__(256) void scale_kernel(
    const float* __restrict__ x0, const int2* __restrict__ meta,
    vfloat4* __restrict__ g0c) {
    const int idx = blockIdx.x * 256 + threadIdx.x;   // < 10*192*32
    const int u4 = idx & 31;
    const int r = (idx >> 5) % P_TOT;
    const int e = idx / (P_TOT * 32);
    const int2 m = meta[r];
    const int w = m.x & 0x1FF;
    const float c = __int_as_float(m.y);
    const vfloat4 v = ((const vfloat4*)x0)[((long)e * C_DIM + w) * 32 + u4];
    g0c[idx] = c * v;
}

// ---------------------------------------------------------------------------
// Main kernel: block = 1024 threads = 16 waves = 2 batch rows (the structure
// that measured 437-440 us).  Wave w owns output segment (w + blockIdx)&15
// for BOTH rows -- rotation breaks the persistent segment->SIMD affinity so
// heavy segments don't always land on the same SIMD.  Lanes 0-31 = row 0,
// lanes 32-63 = row 1, float4 per lane (b128 LDS reads).
// x0-side reads come from the prescaled g0c table with addresses linear in
// p: independent of the meta read, contiguous 512B per path -> L2 streams.
// LDS 33 kB, launch_bounds(1024,8) -> 2 blocks/CU = 32 waves/CU = 100% occ.
// ---------------------------------------------------------------------------
__global__ __launch_bounds__(1024, 8) void contract_kernel(
    const vfloat4* __restrict__ g0c, const int* __restrict__ i0,
    const float* __restrict__ x1, const int* __restrict__ soff,
    const int2* __restrict__ gmeta, float* __restrict__ out) {
    __shared__ vfloat4 x1s[2 * S_DIM * 32];  // [row][s][chunk], 32 kB
    __shared__ int smeta[P_TOT];             // s-indices only, 768 B
    __shared__ int soffs[49];

    const int tid = threadIdx.x;
    const int wave = tid >> 6;
    const int lane = tid & 63;
    const int h = lane >> 5;     // row within the pair
    const int ch = lane & 31;    // float4 chunk (covers U=128)
    const long b0 = (long)blockIdx.x * 2;

    // Stage 2 rows of x1 (2048 float4, coalesced 16B/lane) + meta/soff copy.
    const vfloat4* x1p = (const vfloat4*)(x1 + b0 * (S_DIM * U_DIM));
    x1s[tid] = x1p[tid];
    x1s[tid + 1024] = x1p[tid + 1024];
    if (tid < P_TOT) smeta[tid] = gmeta[tid].x;
    if (tid < 49) soffs[tid] = soff[tid];

    const int elem = i0[b0 + h];
    const vfloat4* gsegp = g0c + (long)elem * (P_TOT * 32) + ch;
    const vfloat4* myx1 = x1s + h * (S_DIM * 32) + ch;

    __syncthreads();

    const int sg = (wave + (int)blockIdx.x) & 15;  // rotated output segment
    int p = soffs[sg * 3];
    const int e1 = soffs[sg * 3 + 1];
    const int e2 = soffs[sg * 3 + 2];
    const int e3 = soffs[sg * 3 + 3];

    vfloat4 acc = (vfloat4)(0.f);

    // degree-1 run (x0 address linear in p: loads issue ahead of meta read)
#pragma unroll 2
    for (; p < e1; ++p) {
        int mx = smeta[p];
        vfloat4 g = gsegp[p * 32];
        vfloat4 xa = myx1[((mx >> 9) & 31) * 32];
        acc += g * xa;
    }
    // degree-2 run
#pragma unroll 2
    for (; p < e2; ++p) {
        int mx = smeta[p];
        vfloat4 g = gsegp[p * 32];
        vfloat4 xa = myx1[((mx >> 9) & 31) * 32];
        vfloat4 xb = myx1[((mx >> 14) & 31) * 32];
        acc += g * (xa * xb);
    }
    // degree-3 run (longest: avg ~6 paths -> deeper unroll, more L2 loads in flight)
#pragma unroll 4
    for (; p < e3; ++p) {
        int mx = smeta[p];
        vfloat4 g = gsegp[p * 32];
        vfloat4 xa = myx1[((mx >> 9) & 31) * 32];
        vfloat4 xb = myx1[((mx >> 14) & 31) * 32];
        vfloat4 xc = myx1[((mx >> 19) & 31) * 32];
        acc += g * (xa * xb * xc);
    }

    // Streamed output (no reuse): nontemporal, coalesced 512B per half-wave.
    vfloat4* outp = (vfloat4*)(out + (b0 + h) * (NUM_OUT_SEG * U_DIM)) + sg * 32 + ch;
    __builtin_nontemporal_store(acc, outp);
}

extern "C" void kernel_launch(void* const* d_in, const int* in_sizes, int n_in,
                              void* d_out, int out_size, void* d_ws, size_t ws_size,
                              hipStream_t stream) {
    const float* x0 = (const float*)d_in[0];
    const int* i0 = (const int*)d_in[1];
    const float* x1 = (const float*)d_in[2];
    const int* idx1 = (const int*)d_in[3];
    const int* w1 = (const int*)d_in[4];
    const int* o1 = (const int*)d_in[5];
    const float* c1 = (const float*)d_in[6];
    const int* idx2 = (const int*)d_in[7];
    const int* w2 = (const int*)d_in[8];
    const int* o2 = (const int*)d_in[9];
    const float* c2 = (const float*)d_in[10];
    const int* idx3 = (const int*)d_in[11];
    const int* w3 = (const int*)d_in[12];
    const int* o3 = (const int*)d_in[13];
    const float* c3 = (const float*)d_in[14];

    int* soff = (int*)d_ws;
    int2* meta = (int2*)((char*)d_ws + 256);
    vfloat4* g0c = (vfloat4*)((char*)d_ws + 4096);  // 983 KB prescaled table

    const int B = in_sizes[1];  // 16384

    prep_kernel<<<1, 256, 0, stream>>>(idx1, w1, o1, c1, idx2, w2, o2, c2,
                                       idx3, w3, o3, c3, soff, meta);
    scale_kernel<<<(NUM_X0 * P_TOT * 32) / 256, 256, 0, stream>>>(x0, meta, g0c);
    contract_kernel<<<B / 2, 1024, 0, stream>>>(g0c, i0, x1, soff, meta, (float*)d_out);
}